// Round 1
// baseline (1236.747 us; speedup 1.0000x reference)
//
#include <hip/hip_runtime.h>
#include <hip/hip_bf16.h>
#include <stddef.h>
#include <stdint.h>

// ---------------------------------------------------------------------------
// Problem constants (from setup_inputs)
// ---------------------------------------------------------------------------
constexpr int NQ = 8192, NI = 8192, NTT = 4096, DIM = 256, DOUT = 128;
constexpr int EQI = 262144, EIT = 131072;
constexpr float BN_EPS = 1e-5f;

// ---------------------------------------------------------------------------
// Workspace layout (float element offsets). Total ~16.9M floats = ~67.4 MB.
// ---------------------------------------------------------------------------
constexpr size_t O_FQW = 0;                                   // feature_q @ W   [NQ,DIM]
constexpr size_t O_FIW = O_FQW + (size_t)NQ * DIM;            // feature_i @ W   [NI,DIM]
constexpr size_t O_FTW = O_FIW + (size_t)NI * DIM;            // feature_t @ W   [NTT,DIM]
constexpr size_t O_HQ  = O_FTW + (size_t)NTT * DIM;           // hidden_q        [NQ,DIM]
constexpr size_t O_HI  = O_HQ + (size_t)NQ * DIM;             // hidden_i        [NI,DIM]
constexpr size_t O_HT  = O_HI + (size_t)NI * DIM;             // hidden_t        [NTT,DIM]
constexpr size_t O_LQ  = O_HT + (size_t)NTT * DIM;            // h_q/embed_q     [NQ,DOUT]
constexpr size_t O_LI  = O_LQ + (size_t)NQ * DOUT;            // h_i/embed_i     [NI,DOUT]
constexpr size_t O_LT  = O_LI + (size_t)NI * DOUT;            // h_t/embed_t     [NTT,DOUT]
constexpr size_t O_EQQ = O_LT + (size_t)NTT * DOUT;           // embed_q @ Q     [NQ,DOUT]
constexpr size_t O_EIQ = O_EQQ + (size_t)NQ * DOUT;           // embed_i @ Q     [NI,DOUT]
constexpr size_t O_STAT = O_EIQ + (size_t)NI * DOUT;          // BN stats 3*(128 sum +128 sumsq)
// CSR A: qi edges keyed by qi_src (n=NQ), other=qi_dst  -> hidden_q
constexpr size_t O_A_OFF = O_STAT + 1024;
constexpr size_t O_A_CUR = O_A_OFF + 8200;
constexpr size_t O_A_COL = O_A_CUR + 8200;
constexpr size_t O_A_VAL = O_A_COL + EQI;
// CSR B: qi edges keyed by qi_dst (n=NI), other=qi_src  -> hi_from_q
constexpr size_t O_B_OFF = O_A_VAL + EQI;
constexpr size_t O_B_CUR = O_B_OFF + 8200;
constexpr size_t O_B_COL = O_B_CUR + 8200;
constexpr size_t O_B_VAL = O_B_COL + EQI;
// CSR C: it edges keyed by it_src (n=NI), other=it_dst  -> hi_from_t
constexpr size_t O_C_OFF = O_B_VAL + EQI;
constexpr size_t O_C_CUR = O_C_OFF + 8200;
constexpr size_t O_C_COL = O_C_CUR + 8200;
constexpr size_t O_C_VAL = O_C_COL + EIT;
// CSR D: it edges keyed by it_dst (n=NTT), other=it_src -> hidden_t
constexpr size_t O_D_OFF = O_C_VAL + EIT;
constexpr size_t O_D_CUR = O_D_OFF + 4104;
constexpr size_t O_D_COL = O_D_CUR + 4104;
constexpr size_t O_D_VAL = O_D_COL + EIT;

// ---------------------------------------------------------------------------
// Counting-sort CSR build
// ---------------------------------------------------------------------------
__global__ __launch_bounds__(256) void hist_kernel(const int* __restrict__ key, int E,
                                                   int* __restrict__ count) {
    int e = blockIdx.x * 256 + threadIdx.x;
    if (e < E) atomicAdd(&count[key[e]], 1);
}

// Exclusive scan over cnt[0..n) -> offs[0..n] and cursor[0..n). cnt may alias cursor.
__global__ __launch_bounds__(1024) void scan_kernel(const int* __restrict__ cnt, int n,
                                                    int* __restrict__ offs,
                                                    int* __restrict__ cursor) {
    __shared__ int sdata[1024];
    __shared__ int s_carry;
    const int t = threadIdx.x;
    if (t == 0) s_carry = 0;
    __syncthreads();
    for (int base = 0; base < n; base += 1024) {
        int v = (base + t < n) ? cnt[base + t] : 0;
        sdata[t] = v;
        __syncthreads();
        for (int off = 1; off < 1024; off <<= 1) {
            int x = (t >= off) ? sdata[t - off] : 0;
            __syncthreads();
            sdata[t] += x;
            __syncthreads();
        }
        int incl = sdata[t];
        int carry = s_carry;
        __syncthreads();
        if (base + t < n) {
            offs[base + t] = carry + incl - v;
            cursor[base + t] = carry + incl - v;
        }
        if (t == 1023) s_carry = carry + incl;
        __syncthreads();
    }
    if (t == 0) offs[n] = s_carry;
}

__global__ __launch_bounds__(256) void scatter_kernel(const int* __restrict__ key,
                                                      const int* __restrict__ other,
                                                      const float* __restrict__ val, int E,
                                                      int* __restrict__ cursor,
                                                      int* __restrict__ scol,
                                                      float* __restrict__ sval) {
    int e = blockIdx.x * 256 + threadIdx.x;
    if (e < E) {
        int p = atomicAdd(&cursor[key[e]], 1);
        scol[p] = other[e];
        sval[p] = val[e];
    }
}

// ---------------------------------------------------------------------------
// CSR SPMM: Y[r,:] (+)= sum_j val[j] * X[col[j],:]   (D = 256, block = 256 thr)
// ---------------------------------------------------------------------------
template <int ACCUM, int RELU>
__global__ __launch_bounds__(256) void spmm_csr_kernel(const int* __restrict__ offs,
                                                       const int* __restrict__ cols,
                                                       const float* __restrict__ vals,
                                                       const float* __restrict__ X,
                                                       float* __restrict__ Y) {
    const int r = blockIdx.x;
    const int t = threadIdx.x;
    float acc = 0.f;
    const int s = offs[r], e = offs[r + 1];
    for (int j = s; j < e; j++) {
        const int c = cols[j];
        const float v = vals[j];
        acc = fmaf(v, X[(size_t)c * DIM + t], acc);
    }
    float* yp = Y + (size_t)r * DIM + t;
    if (ACCUM) acc += *yp;
    if (RELU) acc = fmaxf(acc, 0.f);
    *yp = acc;
}

// ---------------------------------------------------------------------------
// f32 tiled GEMMs: 64x64 tile, BK=16, 256 threads, 4x4 per thread
// ---------------------------------------------------------------------------
constexpr int BM = 64, BN = 64, BK = 16;

// C[M,N] = A[M,K] * B[K,N]  (row-major, M%64==0, N%64==0, K%16==0)
__global__ __launch_bounds__(256) void gemm_nn_kernel(const float* __restrict__ A,
                                                      const float* __restrict__ B,
                                                      float* __restrict__ C, int M, int N, int K,
                                                      int lda, int ldb, int ldc) {
    __shared__ alignas(16) float As[BK][BM + 4];
    __shared__ alignas(16) float Bs[BK][BN + 4];
    const int tid = threadIdx.x;
    const int m0 = blockIdx.y * BM;
    const int n0 = blockIdx.x * BN;
    const int tx = tid & 15;   // n sub-tile
    const int ty = tid >> 4;   // m sub-tile
    const int ar = tid >> 2;            // A-load row 0..63
    const int akv = (tid & 3) * 4;      // A-load k 0,4,8,12
    const int bk = tid >> 4;            // B-load k 0..15
    const int bnv = (tid & 15) * 4;     // B-load n 0..60
    float acc[4][4] = {};
    for (int k0 = 0; k0 < K; k0 += BK) {
        float4 av = *(const float4*)(A + (size_t)(m0 + ar) * lda + k0 + akv);
        float4 bv = *(const float4*)(B + (size_t)(k0 + bk) * ldb + n0 + bnv);
        As[akv + 0][ar] = av.x;
        As[akv + 1][ar] = av.y;
        As[akv + 2][ar] = av.z;
        As[akv + 3][ar] = av.w;
        *(float4*)&Bs[bk][bnv] = bv;
        __syncthreads();
#pragma unroll
        for (int kk = 0; kk < BK; kk++) {
            float4 a4 = *(const float4*)&As[kk][ty * 4];
            float4 b4 = *(const float4*)&Bs[kk][tx * 4];
            float aa[4] = {a4.x, a4.y, a4.z, a4.w};
            float bb[4] = {b4.x, b4.y, b4.z, b4.w};
#pragma unroll
            for (int i = 0; i < 4; i++)
#pragma unroll
                for (int j = 0; j < 4; j++) acc[i][j] = fmaf(aa[i], bb[j], acc[i][j]);
        }
        __syncthreads();
    }
#pragma unroll
    for (int i = 0; i < 4; i++) {
        float* cp = C + (size_t)(m0 + ty * 4 + i) * ldc + n0 + tx * 4;
        *(float4*)cp = make_float4(acc[i][0], acc[i][1], acc[i][2], acc[i][3]);
    }
}

// C[M,N] (+)= A[M,K] * B[N,K]^T (+ bias[n])  (row-major)
template <int BIAS, int ACCUM>
__global__ __launch_bounds__(256) void gemm_nt_kernel(const float* __restrict__ A,
                                                      const float* __restrict__ B,
                                                      const float* __restrict__ bias,
                                                      float* __restrict__ C, int M, int N, int K,
                                                      int lda, int ldb, int ldc) {
    __shared__ alignas(16) float As[BK][BM + 4];
    __shared__ alignas(16) float Bs[BK][BN + 4];
    const int tid = threadIdx.x;
    const int m0 = blockIdx.y * BM;
    const int n0 = blockIdx.x * BN;
    const int tx = tid & 15;
    const int ty = tid >> 4;
    const int ar = tid >> 2;         // row (m for A, n for B) 0..63
    const int akv = (tid & 3) * 4;   // k 0,4,8,12
    float acc[4][4] = {};
    for (int k0 = 0; k0 < K; k0 += BK) {
        float4 av = *(const float4*)(A + (size_t)(m0 + ar) * lda + k0 + akv);
        float4 bv = *(const float4*)(B + (size_t)(n0 + ar) * ldb + k0 + akv);
        As[akv + 0][ar] = av.x;
        As[akv + 1][ar] = av.y;
        As[akv + 2][ar] = av.z;
        As[akv + 3][ar] = av.w;
        Bs[akv + 0][ar] = bv.x;
        Bs[akv + 1][ar] = bv.y;
        Bs[akv + 2][ar] = bv.z;
        Bs[akv + 3][ar] = bv.w;
        __syncthreads();
#pragma unroll
        for (int kk = 0; kk < BK; kk++) {
            float4 a4 = *(const float4*)&As[kk][ty * 4];
            float4 b4 = *(const float4*)&Bs[kk][tx * 4];
            float aa[4] = {a4.x, a4.y, a4.z, a4.w};
            float bb[4] = {b4.x, b4.y, b4.z, b4.w};
#pragma unroll
            for (int i = 0; i < 4; i++)
#pragma unroll
                for (int j = 0; j < 4; j++) acc[i][j] = fmaf(aa[i], bb[j], acc[i][j]);
        }
        __syncthreads();
    }
#pragma unroll
    for (int i = 0; i < 4; i++) {
        float* cp = C + (size_t)(m0 + ty * 4 + i) * ldc + n0 + tx * 4;
        float4 v = make_float4(acc[i][0], acc[i][1], acc[i][2], acc[i][3]);
        if (BIAS) {
            v.x += bias[n0 + tx * 4 + 0];
            v.y += bias[n0 + tx * 4 + 1];
            v.z += bias[n0 + tx * 4 + 2];
            v.w += bias[n0 + tx * 4 + 3];
        }
        if (ACCUM) {
            float4 old = *(const float4*)cp;
            v.x += old.x; v.y += old.y; v.z += old.z; v.w += old.w;
        }
        *(float4*)cp = v;
    }
}

// ---------------------------------------------------------------------------
// BatchNorm (training-mode, biased var) + ReLU, in place on h [N,128]
// ---------------------------------------------------------------------------
__global__ __launch_bounds__(256) void bn_stats_kernel(const float* __restrict__ h, int N,
                                                       float* __restrict__ stats) {
    const int o = blockIdx.x;   // column 0..127
    const int t = threadIdx.x;
    float s = 0.f, ss = 0.f;
    for (int r = t; r < N; r += 256) {
        float v = h[(size_t)r * DOUT + o];
        s += v;
        ss += v * v;
    }
    __shared__ float rs[256], rss[256];
    rs[t] = s;
    rss[t] = ss;
    __syncthreads();
    for (int w = 128; w > 0; w >>= 1) {
        if (t < w) {
            rs[t] += rs[t + w];
            rss[t] += rss[t + w];
        }
        __syncthreads();
    }
    if (t == 0) {
        stats[o] = rs[0];
        stats[DOUT + o] = rss[0];
    }
}

__global__ __launch_bounds__(256) void bn_apply_kernel(float* __restrict__ h, int N,
                                                       const float* __restrict__ stats,
                                                       const float* __restrict__ g,
                                                       const float* __restrict__ beta) {
    const size_t idx = (size_t)blockIdx.x * 256 + threadIdx.x;
    if (idx < (size_t)N * DOUT) {
        const int o = (int)(idx & (DOUT - 1));
        const float inv_n = 1.0f / (float)N;
        const float mu = stats[o] * inv_n;
        const float var = stats[DOUT + o] * inv_n - mu * mu;
        float v = (h[idx] - mu) * rsqrtf(var + BN_EPS) * g[o] + beta[o];
        h[idx] = fmaxf(v, 0.f);
    }
}

// ---------------------------------------------------------------------------
// Launch
// ---------------------------------------------------------------------------
extern "C" void kernel_launch(void* const* d_in, const int* in_sizes, int n_in, void* d_out,
                              int out_size, void* d_ws, size_t ws_size, hipStream_t stream) {
    const float* feature_q = (const float*)d_in[0];
    const float* feature_i = (const float*)d_in[1];
    const float* feature_t = (const float*)d_in[2];
    const int* qi_src = (const int*)d_in[3];
    const int* qi_dst = (const int*)d_in[4];
    const float* qi_val = (const float*)d_in[5];
    const int* it_src = (const int*)d_in[6];
    const int* it_dst = (const int*)d_in[7];
    const float* it_val = (const float*)d_in[8];
    const float* W = (const float*)d_in[9];
    const float* Wq = (const float*)d_in[10];
    const float* bq = (const float*)d_in[11];
    const float* gq = (const float*)d_in[12];
    const float* betaq = (const float*)d_in[13];
    const float* Wi = (const float*)d_in[14];
    const float* bi = (const float*)d_in[15];
    const float* gi = (const float*)d_in[16];
    const float* betai = (const float*)d_in[17];
    const float* Wt = (const float*)d_in[18];
    const float* bt = (const float*)d_in[19];
    const float* gt = (const float*)d_in[20];
    const float* betat = (const float*)d_in[21];
    const float* Qm = (const float*)d_in[22];
    float* out = (float*)d_out;
    float* ws = (float*)d_ws;

    int* Aoff = (int*)(ws + O_A_OFF); int* Acur = (int*)(ws + O_A_CUR);
    int* Acol = (int*)(ws + O_A_COL); float* Aval = ws + O_A_VAL;
    int* Boff = (int*)(ws + O_B_OFF); int* Bcur = (int*)(ws + O_B_CUR);
    int* Bcol = (int*)(ws + O_B_COL); float* Bval = ws + O_B_VAL;
    int* Coff = (int*)(ws + O_C_OFF); int* Ccur = (int*)(ws + O_C_CUR);
    int* Ccol = (int*)(ws + O_C_COL); float* Cval = ws + O_C_VAL;
    int* Doff = (int*)(ws + O_D_OFF); int* Dcur = (int*)(ws + O_D_CUR);
    int* Dcol = (int*)(ws + O_D_COL); float* Dval = ws + O_D_VAL;

    // ---- CSR builds (counts accumulate into cursor buffers; must zero) ----
    hipMemsetAsync(Acur, 0, 8200 * sizeof(int), stream);
    hipMemsetAsync(Bcur, 0, 8200 * sizeof(int), stream);
    hipMemsetAsync(Ccur, 0, 8200 * sizeof(int), stream);
    hipMemsetAsync(Dcur, 0, 4104 * sizeof(int), stream);

    hist_kernel<<<EQI / 256, 256, 0, stream>>>(qi_src, EQI, Acur);
    hist_kernel<<<EQI / 256, 256, 0, stream>>>(qi_dst, EQI, Bcur);
    hist_kernel<<<EIT / 256, 256, 0, stream>>>(it_src, EIT, Ccur);
    hist_kernel<<<EIT / 256, 256, 0, stream>>>(it_dst, EIT, Dcur);

    scan_kernel<<<1, 1024, 0, stream>>>(Acur, NQ, Aoff, Acur);
    scan_kernel<<<1, 1024, 0, stream>>>(Bcur, NI, Boff, Bcur);
    scan_kernel<<<1, 1024, 0, stream>>>(Ccur, NI, Coff, Ccur);
    scan_kernel<<<1, 1024, 0, stream>>>(Dcur, NTT, Doff, Dcur);

    scatter_kernel<<<EQI / 256, 256, 0, stream>>>(qi_src, qi_dst, qi_val, EQI, Acur, Acol, Aval);
    scatter_kernel<<<EQI / 256, 256, 0, stream>>>(qi_dst, qi_src, qi_val, EQI, Bcur, Bcol, Bval);
    scatter_kernel<<<EIT / 256, 256, 0, stream>>>(it_src, it_dst, it_val, EIT, Ccur, Ccol, Cval);
    scatter_kernel<<<EIT / 256, 256, 0, stream>>>(it_dst, it_src, it_val, EIT, Dcur, Dcol, Dval);

    // ---- dense projections X @ W ----
    gemm_nn_kernel<<<dim3(DIM / BN, NQ / BM), 256, 0, stream>>>(feature_q, W, ws + O_FQW, NQ, DIM,
                                                                DIM, DIM, DIM, DIM);
    gemm_nn_kernel<<<dim3(DIM / BN, NI / BM), 256, 0, stream>>>(feature_i, W, ws + O_FIW, NI, DIM,
                                                                DIM, DIM, DIM, DIM);
    gemm_nn_kernel<<<dim3(DIM / BN, NTT / BM), 256, 0, stream>>>(feature_t, W, ws + O_FTW, NTT,
                                                                 DIM, DIM, DIM, DIM, DIM);

    // ---- sparse aggregations ----
    // hidden_q = relu( M_qi @ fiW )
    spmm_csr_kernel<0, 1><<<NQ, 256, 0, stream>>>(Aoff, Acol, Aval, ws + O_FIW, ws + O_HQ);
    // hidden_i = relu( M_qi^T @ fqW + M_it @ ftW )
    spmm_csr_kernel<0, 0><<<NI, 256, 0, stream>>>(Boff, Bcol, Bval, ws + O_FQW, ws + O_HI);
    spmm_csr_kernel<1, 1><<<NI, 256, 0, stream>>>(Coff, Ccol, Cval, ws + O_FTW, ws + O_HI);
    // hidden_t = relu( M_it^T @ fiW )
    spmm_csr_kernel<0, 1><<<NTT, 256, 0, stream>>>(Doff, Dcol, Dval, ws + O_FIW, ws + O_HT);

    // ---- concat-linear: h = [hidden, feature] @ Wx^T + b ----
    gemm_nt_kernel<1, 0><<<dim3(DOUT / BN, NQ / BM), 256, 0, stream>>>(
        ws + O_HQ, Wq, bq, ws + O_LQ, NQ, DOUT, DIM, DIM, 2 * DIM, DOUT);
    gemm_nt_kernel<0, 1><<<dim3(DOUT / BN, NQ / BM), 256, 0, stream>>>(
        feature_q, Wq + DIM, nullptr, ws + O_LQ, NQ, DOUT, DIM, DIM, 2 * DIM, DOUT);
    gemm_nt_kernel<1, 0><<<dim3(DOUT / BN, NI / BM), 256, 0, stream>>>(
        ws + O_HI, Wi, bi, ws + O_LI, NI, DOUT, DIM, DIM, 2 * DIM, DOUT);
    gemm_nt_kernel<0, 1><<<dim3(DOUT / BN, NI / BM), 256, 0, stream>>>(
        feature_i, Wi + DIM, nullptr, ws + O_LI, NI, DOUT, DIM, DIM, 2 * DIM, DOUT);
    gemm_nt_kernel<1, 0><<<dim3(DOUT / BN, NTT / BM), 256, 0, stream>>>(
        ws + O_HT, Wt, bt, ws + O_LT, NTT, DOUT, DIM, DIM, 2 * DIM, DOUT);
    gemm_nt_kernel<0, 1><<<dim3(DOUT / BN, NTT / BM), 256, 0, stream>>>(
        feature_t, Wt + DIM, nullptr, ws + O_LT, NTT, DOUT, DIM, DIM, 2 * DIM, DOUT);

    // ---- BN + ReLU (in place -> embed) ----
    bn_stats_kernel<<<DOUT, 256, 0, stream>>>(ws + O_LQ, NQ, ws + O_STAT + 0);
    bn_stats_kernel<<<DOUT, 256, 0, stream>>>(ws + O_LI, NI, ws + O_STAT + 256);
    bn_stats_kernel<<<DOUT, 256, 0, stream>>>(ws + O_LT, NTT, ws + O_STAT + 512);
    bn_apply_kernel<<<(NQ * DOUT) / 256, 256, 0, stream>>>(ws + O_LQ, NQ, ws + O_STAT + 0, gq,
                                                           betaq);
    bn_apply_kernel<<<(NI * DOUT) / 256, 256, 0, stream>>>(ws + O_LI, NI, ws + O_STAT + 256, gi,
                                                           betai);
    bn_apply_kernel<<<(NTT * DOUT) / 256, 256, 0, stream>>>(ws + O_LT, NTT, ws + O_STAT + 512, gt,
                                                            betat);

    // ---- embed @ Q ----
    gemm_nn_kernel<<<dim3(DOUT / BN, NQ / BM), 256, 0, stream>>>(ws + O_LQ, Qm, ws + O_EQQ, NQ,
                                                                 DOUT, DOUT, DOUT, DOUT, DOUT);
    gemm_nn_kernel<<<dim3(DOUT / BN, NI / BM), 256, 0, stream>>>(ws + O_LI, Qm, ws + O_EIQ, NI,
                                                                 DOUT, DOUT, DOUT, DOUT, DOUT);

    // ---- scores ----
    // score_qi = (embed_q @ Q) @ embed_i^T   [NQ, NI]
    gemm_nt_kernel<0, 0><<<dim3(NI / BN, NQ / BM), 256, 0, stream>>>(
        ws + O_EQQ, ws + O_LI, nullptr, out, NQ, NI, DOUT, DOUT, DOUT, NI);
    // score_it = (embed_i @ Q) @ embed_t^T   [NI, NTT]
    gemm_nt_kernel<0, 0><<<dim3(NTT / BN, NI / BM), 256, 0, stream>>>(
        ws + O_EIQ, ws + O_LT, nullptr, out + (size_t)NQ * NI, NI, NTT, DOUT, DOUT, DOUT, NTT);
}

// Round 2
// 890.517 us; speedup vs baseline: 1.3888x; 1.3888x over previous
//
#include <hip/hip_runtime.h>
#include <stddef.h>
#include <stdint.h>

using u16 = unsigned short;
typedef __attribute__((ext_vector_type(8))) short short8;
typedef __attribute__((ext_vector_type(4))) float f32x4;

// ---------------------------------------------------------------------------
// Problem constants
// ---------------------------------------------------------------------------
constexpr int NQ = 8192, NI = 8192, NTT = 4096, DIM = 256, DOUT = 128;
constexpr int EQI = 262144, EIT = 131072, EB = EQI + EIT;
constexpr float BN_EPS = 1e-5f;

// ---------------------------------------------------------------------------
// Workspace byte offsets
// ---------------------------------------------------------------------------
constexpr size_t al(size_t x) { return (x + 255) & ~(size_t)255; }
constexpr size_t BO_FQW = 0;                                   // bf16 [NQ,256]
constexpr size_t BO_FTW = BO_FQW + (size_t)NQ * DIM * 2;       // bf16 [NTT,256] (MUST be contiguous after FQW)
constexpr size_t BO_FIW = al(BO_FTW + (size_t)NTT * DIM * 2);  // bf16 [NI,256]
constexpr size_t BO_CQ  = al(BO_FIW + (size_t)NI * DIM * 2);   // bf16 [NQ,512] concat
constexpr size_t BO_CI  = al(BO_CQ + (size_t)NQ * 512 * 2);    // bf16 [NI,512]
constexpr size_t BO_CT  = al(BO_CI + (size_t)NI * 512 * 2);    // bf16 [NTT,512]
constexpr size_t BO_LQ  = al(BO_CT + (size_t)NTT * 512 * 2);   // f32  [NQ,128]
constexpr size_t BO_LI  = al(BO_LQ + (size_t)NQ * DOUT * 4);
constexpr size_t BO_LT  = al(BO_LI + (size_t)NI * DOUT * 4);
constexpr size_t BO_EQB = al(BO_LT + (size_t)NTT * DOUT * 4);  // bf16 embed_q [NQ,128]
constexpr size_t BO_EIB = al(BO_EQB + (size_t)NQ * DOUT * 2);
constexpr size_t BO_ETB = al(BO_EIB + (size_t)NI * DOUT * 2);
constexpr size_t BO_EQQ = al(BO_ETB + (size_t)NTT * DOUT * 2); // bf16 embed_q@Q [NQ,128]
constexpr size_t BO_EIQ = al(BO_EQQ + (size_t)NQ * DOUT * 2);
constexpr size_t BO_WTR = al(BO_EIQ + (size_t)NI * DOUT * 2);  // bf16 W^T [256,256]
constexpr size_t BO_WXQ = al(BO_WTR + (size_t)DIM * DIM * 2);  // bf16 Wq [128,512]
constexpr size_t BO_WXI = al(BO_WXQ + (size_t)DOUT * 512 * 2);
constexpr size_t BO_WXT = al(BO_WXI + (size_t)DOUT * 512 * 2);
constexpr size_t BO_QTR = al(BO_WXT + (size_t)DOUT * 512 * 2); // bf16 Q^T [128,128]
constexpr size_t BO_STAT = al(BO_QTR + (size_t)DOUT * DOUT * 2);  // f32 1024
constexpr size_t BO_AOFF = al(BO_STAT + 1024 * 4);
constexpr size_t BO_ACUR = al(BO_AOFF + (size_t)(NQ + 1) * 4);
constexpr size_t BO_ACOL = al(BO_ACUR + (size_t)NQ * 4);
constexpr size_t BO_AVAL = al(BO_ACOL + (size_t)EQI * 4);
constexpr size_t BO_BOFF = al(BO_AVAL + (size_t)EQI * 4);
constexpr size_t BO_BCUR = al(BO_BOFF + (size_t)(NI + 1) * 4);
constexpr size_t BO_BCOL = al(BO_BCUR + (size_t)NI * 4);
constexpr size_t BO_BVAL = al(BO_BCOL + (size_t)EB * 4);
constexpr size_t BO_DOFF = al(BO_BVAL + (size_t)EB * 4);
constexpr size_t BO_DCUR = al(BO_DOFF + (size_t)(NTT + 1) * 4);
constexpr size_t BO_DCOL = al(BO_DCUR + (size_t)NTT * 4);
constexpr size_t BO_DVAL = al(BO_DCOL + (size_t)EIT * 4);

// ---------------------------------------------------------------------------
// bf16 helpers (RNE)
// ---------------------------------------------------------------------------
__device__ __forceinline__ u16 f2bf(float f) {
    union { float f; uint32_t u; } v;
    v.f = f;
    uint32_t u = v.u;
    u += 0x7FFFu + ((u >> 16) & 1u);
    return (u16)(u >> 16);
}
__device__ __forceinline__ float bf2f(u16 h) {
    union { uint32_t u; float f; } v;
    v.u = (uint32_t)h << 16;
    return v.f;
}

// ---------------------------------------------------------------------------
// Counting-sort CSR build
// ---------------------------------------------------------------------------
__global__ __launch_bounds__(256) void hist_kernel(const int* __restrict__ key, int E,
                                                   int* __restrict__ count) {
    int e = blockIdx.x * 256 + threadIdx.x;
    if (e < E) atomicAdd(&count[key[e]], 1);
}

__global__ __launch_bounds__(1024) void scan_kernel(const int* __restrict__ cnt, int n,
                                                    int* __restrict__ offs,
                                                    int* __restrict__ cursor) {
    __shared__ int sdata[1024];
    __shared__ int s_carry;
    const int t = threadIdx.x;
    if (t == 0) s_carry = 0;
    __syncthreads();
    for (int base = 0; base < n; base += 1024) {
        int v = (base + t < n) ? cnt[base + t] : 0;
        sdata[t] = v;
        __syncthreads();
        for (int off = 1; off < 1024; off <<= 1) {
            int x = (t >= off) ? sdata[t - off] : 0;
            __syncthreads();
            sdata[t] += x;
            __syncthreads();
        }
        int incl = sdata[t];
        int carry = s_carry;
        __syncthreads();
        if (base + t < n) {
            offs[base + t] = carry + incl - v;
            cursor[base + t] = carry + incl - v;
        }
        if (t == 1023) s_carry = carry + incl;
        __syncthreads();
    }
    if (t == 0) offs[n] = s_carry;
}

__global__ __launch_bounds__(256) void scatter_kernel(const int* __restrict__ key,
                                                      const int* __restrict__ other,
                                                      const float* __restrict__ val, int E,
                                                      int col_offset, int* __restrict__ cursor,
                                                      int* __restrict__ scol,
                                                      float* __restrict__ sval) {
    int e = blockIdx.x * 256 + threadIdx.x;
    if (e < E) {
        int p = atomicAdd(&cursor[key[e]], 1);
        scol[p] = other[e] + col_offset;
        sval[p] = val[e];
    }
}

// ---------------------------------------------------------------------------
// CSR SPMM: Y[r, 0:256] = relu( sum_j val[j] * X[col[j], :] ), X bf16, Y bf16
// Y leading dim = 512 (writes left half of concat buffer)
// ---------------------------------------------------------------------------
__global__ __launch_bounds__(256) void spmm_csr_kernel(const int* __restrict__ offs,
                                                       const int* __restrict__ cols,
                                                       const float* __restrict__ vals,
                                                       const u16* __restrict__ X,
                                                       u16* __restrict__ Y) {
    const int r = blockIdx.x;
    const int t = threadIdx.x;
    float acc = 0.f;
    const int s = offs[r], e = offs[r + 1];
    for (int j = s; j < e; j++) {
        const int c = cols[j];
        const float v = vals[j];
        acc = fmaf(v, bf2f(X[(size_t)c * DIM + t]), acc);
    }
    Y[(size_t)r * 512 + t] = f2bf(fmaxf(acc, 0.f));
}

// ---------------------------------------------------------------------------
// Conversions
// ---------------------------------------------------------------------------
// features f32 [rows,256] -> bf16 into right half of concat buffer (ld 512)
__global__ __launch_bounds__(256) void cvt_feat_kernel(const float* __restrict__ src,
                                                       u16* __restrict__ dst_half, int total) {
    int idx = blockIdx.x * 256 + threadIdx.x;
    if (idx < total) {
        int r = idx >> 8, c = idx & 255;
        dst_half[(size_t)r * 512 + c] = f2bf(src[idx]);
    }
}

__global__ __launch_bounds__(256) void cvt_kernel(const float* __restrict__ src,
                                                  u16* __restrict__ dst, int n) {
    int idx = blockIdx.x * 256 + threadIdx.x;
    if (idx < n) dst[idx] = f2bf(src[idx]);
}

// dst[n*dk + k] = src[k*dn + n]  (src [dk,dn] -> dst [dn,dk], both dense)
__global__ __launch_bounds__(256) void transpose_cvt_kernel(const float* __restrict__ src,
                                                            u16* __restrict__ dst, int dn,
                                                            int dk) {
    int idx = blockIdx.x * 256 + threadIdx.x;
    if (idx < dn * dk) {
        int n = idx / dk, k = idx - n * dk;
        dst[idx] = f2bf(src[(size_t)k * dn + n]);
    }
}

// ---------------------------------------------------------------------------
// bf16 NT MFMA GEMM: C[M,N] = A[M,K] @ B[N,K]^T
// 128x128 tile, 256 threads (4 waves 2x2), BK=64, global_load_lds staging
// with row-rotation block swizzle. M,N multiples of 128; K multiple of 64.
// ---------------------------------------------------------------------------
template <int OUT_BF16>
__global__ __launch_bounds__(256) void gemm_bf16_nt(const u16* __restrict__ A,
                                                    const u16* __restrict__ B,
                                                    void* __restrict__ Cout, int K, int lda,
                                                    int ldb, int ldc) {
    __shared__ alignas(16) u16 As[128 * 64];
    __shared__ alignas(16) u16 Bs[128 * 64];
    const int tid = threadIdx.x;
    const int l = tid & 63;
    const int w = tid >> 6;
    const size_t m0 = (size_t)blockIdx.y * 128;
    const size_t n0 = (size_t)blockIdx.x * 128;
    const int lr = l >> 3;               // staging row-in-group 0..7
    const int skb = ((l & 7) - lr) & 7;  // global k-block this lane fetches (rotated)
    const u16* Ag = A + (m0 + (size_t)(w * 32 + lr)) * lda + skb * 8;
    const u16* Bg = B + (n0 + (size_t)(w * 32 + lr)) * ldb + skb * 8;
    u16* ldsA = As + (w * 32) * 64;
    u16* ldsB = Bs + (w * 32) * 64;

    const int fr = l & 15;  // fragment row (m or n)
    const int fq = l >> 4;  // quad 0..3
    const int wmr = (w >> 1) * 64;
    const int wnr = (w & 1) * 64;

    f32x4 acc[4][4] = {};

    for (int k0 = 0; k0 < K; k0 += 64) {
#pragma unroll
        for (int t = 0; t < 4; t++) {
            __builtin_amdgcn_global_load_lds(
                (const __attribute__((address_space(1))) void*)(Ag + (size_t)t * 8 * lda + k0),
                (__attribute__((address_space(3))) void*)(ldsA + t * 8 * 64), 16, 0, 0);
            __builtin_amdgcn_global_load_lds(
                (const __attribute__((address_space(1))) void*)(Bg + (size_t)t * 8 * ldb + k0),
                (__attribute__((address_space(3))) void*)(ldsB + t * 8 * 64), 16, 0, 0);
        }
        __syncthreads();
#pragma unroll
        for (int ks = 0; ks < 2; ks++) {
            const int kb = ks * 4 + fq;  // k-block 0..7 within BK tile
            short8 af[4], bf[4];
#pragma unroll
            for (int mt = 0; mt < 4; mt++) {
                const int r = wmr + mt * 16 + fr;
                af[mt] = *(const short8*)(As + r * 64 + ((kb + r) & 7) * 8);
            }
#pragma unroll
            for (int nt = 0; nt < 4; nt++) {
                const int r = wnr + nt * 16 + fr;
                bf[nt] = *(const short8*)(Bs + r * 64 + ((kb + r) & 7) * 8);
            }
#pragma unroll
            for (int mt = 0; mt < 4; mt++)
#pragma unroll
                for (int nt = 0; nt < 4; nt++)
                    acc[mt][nt] = __builtin_amdgcn_mfma_f32_16x16x32_bf16(af[mt], bf[nt],
                                                                          acc[mt][nt], 0, 0, 0);
        }
        __syncthreads();
    }
    // C/D layout: col = lane&15, row = (lane>>4)*4 + reg   [m89/m91 verified]
    const size_t crow = m0 + wmr + fq * 4;
    const size_t ccol = n0 + wnr + fr;
#pragma unroll
    for (int mt = 0; mt < 4; mt++)
#pragma unroll
        for (int nt = 0; nt < 4; nt++)
#pragma unroll
            for (int i = 0; i < 4; i++) {
                size_t r = crow + mt * 16 + i;
                size_t c = ccol + nt * 16;
                if (OUT_BF16)
                    ((u16*)Cout)[r * ldc + c] = f2bf(acc[mt][nt][i]);
                else
                    ((float*)Cout)[r * ldc + c] = acc[mt][nt][i];
            }
}

// ---------------------------------------------------------------------------
// BatchNorm (biased var) + ReLU: stats then apply (f32 in -> bf16 out)
// Note: linear bias cancels in BN (h - mean), so it is never added.
// ---------------------------------------------------------------------------
__global__ __launch_bounds__(256) void bn_stats_kernel(const float* __restrict__ h, int N,
                                                       float* __restrict__ stats) {
    const int o = blockIdx.x;
    const int t = threadIdx.x;
    float s = 0.f, ss = 0.f;
    for (int r = t; r < N; r += 256) {
        float v = h[(size_t)r * DOUT + o];
        s += v;
        ss += v * v;
    }
    __shared__ float rs[256], rss[256];
    rs[t] = s;
    rss[t] = ss;
    __syncthreads();
    for (int wd = 128; wd > 0; wd >>= 1) {
        if (t < wd) {
            rs[t] += rs[t + wd];
            rss[t] += rss[t + wd];
        }
        __syncthreads();
    }
    if (t == 0) {
        stats[o] = rs[0];
        stats[DOUT + o] = rss[0];
    }
}

__global__ __launch_bounds__(256) void bn_apply_kernel(const float* __restrict__ h, int N,
                                                       const float* __restrict__ stats,
                                                       const float* __restrict__ g,
                                                       const float* __restrict__ beta,
                                                       u16* __restrict__ out) {
    const size_t idx = (size_t)blockIdx.x * 256 + threadIdx.x;
    if (idx < (size_t)N * DOUT) {
        const int o = (int)(idx & (DOUT - 1));
        const float inv_n = 1.0f / (float)N;
        const float mu = stats[o] * inv_n;
        const float var = stats[DOUT + o] * inv_n - mu * mu;
        float v = (h[idx] - mu) * rsqrtf(var + BN_EPS) * g[o] + beta[o];
        out[idx] = f2bf(fmaxf(v, 0.f));
    }
}

// ---------------------------------------------------------------------------
// Launch
// ---------------------------------------------------------------------------
extern "C" void kernel_launch(void* const* d_in, const int* in_sizes, int n_in, void* d_out,
                              int out_size, void* d_ws, size_t ws_size, hipStream_t stream) {
    const float* feature_q = (const float*)d_in[0];
    const float* feature_i = (const float*)d_in[1];
    const float* feature_t = (const float*)d_in[2];
    const int* qi_src = (const int*)d_in[3];
    const int* qi_dst = (const int*)d_in[4];
    const float* qi_val = (const float*)d_in[5];
    const int* it_src = (const int*)d_in[6];
    const int* it_dst = (const int*)d_in[7];
    const float* it_val = (const float*)d_in[8];
    const float* W = (const float*)d_in[9];
    const float* Wq = (const float*)d_in[10];
    const float* gq = (const float*)d_in[12];
    const float* betaq = (const float*)d_in[13];
    const float* Wi = (const float*)d_in[14];
    const float* gi = (const float*)d_in[16];
    const float* betai = (const float*)d_in[17];
    const float* Wt = (const float*)d_in[18];
    const float* gt = (const float*)d_in[20];
    const float* betat = (const float*)d_in[21];
    const float* Qm = (const float*)d_in[22];
    float* out = (float*)d_out;
    char* ws = (char*)d_ws;

    u16* FQW = (u16*)(ws + BO_FQW);   // rows 0..NQ-1 of combined [fqW; ftW]
    u16* FIW = (u16*)(ws + BO_FIW);
    u16* FTW = (u16*)(ws + BO_FTW);
    u16* CQ = (u16*)(ws + BO_CQ);
    u16* CI = (u16*)(ws + BO_CI);
    u16* CT = (u16*)(ws + BO_CT);
    float* LQ = (float*)(ws + BO_LQ);
    float* LI = (float*)(ws + BO_LI);
    float* LT = (float*)(ws + BO_LT);
    u16* EQB = (u16*)(ws + BO_EQB);
    u16* EIB = (u16*)(ws + BO_EIB);
    u16* ETB = (u16*)(ws + BO_ETB);
    u16* EQQ = (u16*)(ws + BO_EQQ);
    u16* EIQ = (u16*)(ws + BO_EIQ);
    u16* WTR = (u16*)(ws + BO_WTR);
    u16* WXQ = (u16*)(ws + BO_WXQ);
    u16* WXI = (u16*)(ws + BO_WXI);
    u16* WXT = (u16*)(ws + BO_WXT);
    u16* QTR = (u16*)(ws + BO_QTR);
    float* STAT = (float*)(ws + BO_STAT);
    int* Aoff = (int*)(ws + BO_AOFF); int* Acur = (int*)(ws + BO_ACUR);
    int* Acol = (int*)(ws + BO_ACOL); float* Aval = (float*)(ws + BO_AVAL);
    int* Boff = (int*)(ws + BO_BOFF); int* Bcur = (int*)(ws + BO_BCUR);
    int* Bcol = (int*)(ws + BO_BCOL); float* Bval = (float*)(ws + BO_BVAL);
    int* Doff = (int*)(ws + BO_DOFF); int* Dcur = (int*)(ws + BO_DCUR);
    int* Dcol = (int*)(ws + BO_DCOL); float* Dval = (float*)(ws + BO_DVAL);

    // ---- zero CSR counters ----
    hipMemsetAsync(Acur, 0, NQ * sizeof(int), stream);
    hipMemsetAsync(Bcur, 0, NI * sizeof(int), stream);
    hipMemsetAsync(Dcur, 0, NTT * sizeof(int), stream);

    // ---- weight / feature conversions ----
    cvt_feat_kernel<<<NQ, 256, 0, stream>>>(feature_q, CQ + 256, NQ * 256);
    cvt_feat_kernel<<<NI, 256, 0, stream>>>(feature_i, CI + 256, NI * 256);
    cvt_feat_kernel<<<NTT, 256, 0, stream>>>(feature_t, CT + 256, NTT * 256);
    transpose_cvt_kernel<<<(DIM * DIM) / 256, 256, 0, stream>>>(W, WTR, DIM, DIM);
    transpose_cvt_kernel<<<(DOUT * DOUT) / 256, 256, 0, stream>>>(Qm, QTR, DOUT, DOUT);
    cvt_kernel<<<(DOUT * 512) / 256, 256, 0, stream>>>(Wq, WXQ, DOUT * 512);
    cvt_kernel<<<(DOUT * 512) / 256, 256, 0, stream>>>(Wi, WXI, DOUT * 512);
    cvt_kernel<<<(DOUT * 512) / 256, 256, 0, stream>>>(Wt, WXT, DOUT * 512);

    // ---- CSR builds ----
    hist_kernel<<<EQI / 256, 256, 0, stream>>>(qi_src, EQI, Acur);
    hist_kernel<<<EQI / 256, 256, 0, stream>>>(qi_dst, EQI, Bcur);
    hist_kernel<<<EIT / 256, 256, 0, stream>>>(it_src, EIT, Bcur);
    hist_kernel<<<EIT / 256, 256, 0, stream>>>(it_dst, EIT, Dcur);
    scan_kernel<<<1, 1024, 0, stream>>>(Acur, NQ, Aoff, Acur);
    scan_kernel<<<1, 1024, 0, stream>>>(Bcur, NI, Boff, Bcur);
    scan_kernel<<<1, 1024, 0, stream>>>(Dcur, NTT, Doff, Dcur);
    scatter_kernel<<<EQI / 256, 256, 0, stream>>>(qi_src, qi_dst, qi_val, EQI, 0, Acur, Acol, Aval);
    scatter_kernel<<<EQI / 256, 256, 0, stream>>>(qi_dst, qi_src, qi_val, EQI, 0, Bcur, Bcol, Bval);
    scatter_kernel<<<EIT / 256, 256, 0, stream>>>(it_src, it_dst, it_val, EIT, NQ, Bcur, Bcol, Bval);
    scatter_kernel<<<EIT / 256, 256, 0, stream>>>(it_dst, it_src, it_val, EIT, 0, Dcur, Dcol, Dval);

    // ---- projections: feat_bf16 @ W  (NT with W^T), bf16 out ----
    gemm_bf16_nt<1><<<dim3(DIM / 128, NQ / 128), 256, 0, stream>>>(CQ + 256, WTR, FQW, DIM, 512,
                                                                   DIM, DIM);
    gemm_bf16_nt<1><<<dim3(DIM / 128, NI / 128), 256, 0, stream>>>(CI + 256, WTR, FIW, DIM, 512,
                                                                   DIM, DIM);
    gemm_bf16_nt<1><<<dim3(DIM / 128, NTT / 128), 256, 0, stream>>>(CT + 256, WTR, FTW, DIM, 512,
                                                                    DIM, DIM);

    // ---- sparse aggregations -> relu -> bf16 left half of concat ----
    spmm_csr_kernel<<<NQ, 256, 0, stream>>>(Aoff, Acol, Aval, FIW, CQ);
    spmm_csr_kernel<<<NI, 256, 0, stream>>>(Boff, Bcol, Bval, FQW, CI);  // [fqW; ftW] combined
    spmm_csr_kernel<<<NTT, 256, 0, stream>>>(Doff, Dcol, Dval, FIW, CT);

    // ---- concat-linear (bias cancels in BN): [hidden,feat] @ Wx^T, f32 out ----
    gemm_bf16_nt<0><<<dim3(1, NQ / 128), 256, 0, stream>>>(CQ, WXQ, LQ, 512, 512, 512, DOUT);
    gemm_bf16_nt<0><<<dim3(1, NI / 128), 256, 0, stream>>>(CI, WXI, LI, 512, 512, 512, DOUT);
    gemm_bf16_nt<0><<<dim3(1, NTT / 128), 256, 0, stream>>>(CT, WXT, LT, 512, 512, 512, DOUT);

    // ---- BN + ReLU -> bf16 embeds ----
    bn_stats_kernel<<<DOUT, 256, 0, stream>>>(LQ, NQ, STAT + 0);
    bn_stats_kernel<<<DOUT, 256, 0, stream>>>(LI, NI, STAT + 256);
    bn_stats_kernel<<<DOUT, 256, 0, stream>>>(LT, NTT, STAT + 512);
    bn_apply_kernel<<<(NQ * DOUT) / 256, 256, 0, stream>>>(LQ, NQ, STAT + 0, gq, betaq, EQB);
    bn_apply_kernel<<<(NI * DOUT) / 256, 256, 0, stream>>>(LI, NI, STAT + 256, gi, betai, EIB);
    bn_apply_kernel<<<(NTT * DOUT) / 256, 256, 0, stream>>>(LT, NTT, STAT + 512, gt, betat, ETB);

    // ---- embed @ Q (NT with Q^T), bf16 out ----
    gemm_bf16_nt<1><<<dim3(1, NQ / 128), 256, 0, stream>>>(EQB, QTR, EQQ, DOUT, DOUT, DOUT, DOUT);
    gemm_bf16_nt<1><<<dim3(1, NI / 128), 256, 0, stream>>>(EIB, QTR, EIQ, DOUT, DOUT, DOUT, DOUT);

    // ---- scores ----
    gemm_bf16_nt<0><<<dim3(NI / 128, NQ / 128), 256, 0, stream>>>(EQQ, EIB, out, DOUT, DOUT, DOUT,
                                                                  NI);
    gemm_bf16_nt<0><<<dim3(NTT / 128, NI / 128), 256, 0, stream>>>(
        EIQ, ETB, out + (size_t)NQ * NI, DOUT, DOUT, DOUT, NTT);
}